// Round 1
// baseline (160.822 us; speedup 1.0000x reference)
//
#include <hip/hip_runtime.h>
#include <hip/hip_bf16.h>
#include <stdint.h>

#define S_LEN 2048
#define D_DIM 1024
#define P_DIM 256
#define NQ_   8192
#define M_TOT 16384  // B*S

typedef __attribute__((ext_vector_type(4))) float  f32x4;
typedef __attribute__((ext_vector_type(8))) __bf16 bf16x8;
typedef __attribute__((ext_vector_type(4))) __bf16 bf16x4;

// ---------------- Kernel 0: W [1024][256] f32 -> WT [256][1024] bf16 ----------
__global__ __launch_bounds__(1024) void wt_kernel(const float* __restrict__ W,
                                                  __bf16* __restrict__ WT) {
    __shared__ __bf16 tile[32][33];  // +1 pad breaks bank conflicts
    const int k0 = blockIdx.x * 32;
    const int n0 = blockIdx.y * 32;
    const int tx = threadIdx.x, ty = threadIdx.y;
    // coalesced read along n
    tile[ty][tx] = (__bf16)W[(k0 + ty) * P_DIM + (n0 + tx)];
    __syncthreads();
    // coalesced write along k
    WT[(n0 + ty) * D_DIM + (k0 + tx)] = tile[tx][ty];
}

// ---------------- Kernel 1: H = A @ W + b  (bf16 MFMA, fp32 acc) --------------
// BM=64, BN=256, BK=32. grid = 256 blocks (one per CU), 256 threads (4 waves).
// Wave w computes the 64x64 sub-tile at columns [w*64, w*64+64).
__global__ __launch_bounds__(256) void gemm_kernel(const float*  __restrict__ A,
                                                   const __bf16* __restrict__ WT,
                                                   const float*  __restrict__ bias,
                                                   float*        __restrict__ H) {
    __shared__ __bf16 As[64 * 32];    // [m][k]  8 KB
    __shared__ __bf16 Bs[256 * 32];   // [n][k] 16 KB

    const int tid = threadIdx.x;
    const int w   = tid >> 6;   // wave id 0..3
    const int l   = tid & 63;   // lane
    const int lm  = l & 15;     // row/col within a 16-tile
    const int q   = l >> 4;     // quad -> k-offset q*8 for A/B frags

    const int m0 = blockIdx.x * 64;

    f32x4 acc[4][4] = {};  // 64 VGPRs of fp32 accumulator

    for (int k0 = 0; k0 < D_DIM; k0 += 32) {
        // ---- stage A tile (64x32 fp32 -> bf16): 512 float4 chunks, 2/thread
        #pragma unroll
        for (int i = 0; i < 2; ++i) {
            const int ch  = tid + i * 256;
            const int row = ch >> 3;          // 8 float4-chunks per 32-wide row
            const int c4  = (ch & 7) << 2;
            const float4 va = *(const float4*)(A + (size_t)(m0 + row) * D_DIM + k0 + c4);
            bf16x4 vb;
            vb[0] = (__bf16)va.x; vb[1] = (__bf16)va.y;
            vb[2] = (__bf16)va.z; vb[3] = (__bf16)va.w;
            *(bf16x4*)(As + row * 32 + c4) = vb;   // ds_write_b64
        }
        // ---- stage B tile (256x32 bf16): 1024 16B chunks, 4/thread
        #pragma unroll
        for (int i = 0; i < 4; ++i) {
            const int ch = tid + i * 256;
            const int n  = ch >> 2;           // 4 16B-chunks per 32-wide row
            const int c8 = (ch & 3) << 3;
            *(uint4*)(Bs + n * 32 + c8) =
                *(const uint4*)(WT + (size_t)n * D_DIM + k0 + c8);
        }
        __syncthreads();

        // ---- fragment loads (all ds_read_b128, 16B aligned)
        bf16x8 af[4], bfr[4];
        #pragma unroll
        for (int mi = 0; mi < 4; ++mi)
            af[mi] = *(const bf16x8*)(As + (mi * 16 + lm) * 32 + q * 8);
        #pragma unroll
        for (int ni = 0; ni < 4; ++ni)
            bfr[ni] = *(const bf16x8*)(Bs + (w * 64 + ni * 16 + lm) * 32 + q * 8);

        // ---- 16 MFMAs: 64x64x32 per wave per K-step
        #pragma unroll
        for (int mi = 0; mi < 4; ++mi)
            #pragma unroll
            for (int ni = 0; ni < 4; ++ni)
                acc[mi][ni] = __builtin_amdgcn_mfma_f32_16x16x32_bf16(
                    af[mi], bfr[ni], acc[mi][ni], 0, 0, 0);

        __syncthreads();
    }

    // ---- epilogue: D layout row = q*4 + r, col = lane&15 (guide-verified m89)
    #pragma unroll
    for (int ni = 0; ni < 4; ++ni) {
        const int col = w * 64 + ni * 16 + lm;
        const float bv = bias[col];
        #pragma unroll
        for (int mi = 0; mi < 4; ++mi) {
            #pragma unroll
            for (int r = 0; r < 4; ++r) {
                const int row = m0 + mi * 16 + q * 4 + r;
                H[(size_t)row * P_DIM + col] = acc[mi][ni][r] + bv;
            }
        }
    }
}

// ---------------- Kernel 2: span gather -------------------------------------
// One block per query. 256 threads: t -> {set, half, col4}. float4 everywhere.
__global__ __launch_bounds__(256) void gather_kernel(const float* __restrict__ H,
                                                     const int* __restrict__ s1,
                                                     const int* __restrict__ e1,
                                                     const int* __restrict__ qb,
                                                     const int* __restrict__ s2,
                                                     const int* __restrict__ e2,
                                                     float* __restrict__ out) {
    const int qi  = blockIdx.x;
    const int t   = threadIdx.x;
    const int b   = qb[qi];
    const int set = t >> 7;            // 0 -> (s1,e1), 1 -> (s2,e2)
    const int rem = t & 127;
    const int half = rem >> 6;         // 0 -> start row, 1 -> end row
    const int c4  = (rem & 63) << 2;   // float4 column offset

    const int s = set ? s2[qi] : s1[qi];
    const int e = set ? e2[qi] : e1[qi];

    float4 v = make_float4(0.f, 0.f, 0.f, 0.f);
    if (e >= s) {                       // block-uniform-per-half... per-set uniform branch
        const int ridx = half ? e : s;
        v = *(const float4*)(H + ((size_t)b * S_LEN + ridx) * P_DIM + c4);
    }
    *(float4*)(out + (size_t)set * (NQ_ * 512) + (size_t)qi * 512 + half * 256 + c4) = v;
}

// ---------------- launch ------------------------------------------------------
extern "C" void kernel_launch(void* const* d_in, const int* in_sizes, int n_in,
                              void* d_out, int out_size, void* d_ws, size_t ws_size,
                              hipStream_t stream) {
    const float* A    = (const float*)d_in[1];   // encoded_input [8,2048,1024]
    const int*   s1   = (const int*)  d_in[2];
    const int*   e1   = (const int*)  d_in[3];
    const int*   qb   = (const int*)  d_in[4];
    const int*   s2   = (const int*)  d_in[5];
    const int*   e2   = (const int*)  d_in[6];
    const float* W    = (const float*)d_in[7];   // [1024,256]
    const float* bias = (const float*)d_in[8];   // [256]
    float*       out  = (float*)d_out;           // res1 ++ res2, 8388608 floats

    __bf16* WT = (__bf16*)d_ws;                      // 512 KB
    float*  H  = (float*)((char*)d_ws + (1 << 20));  // 16 MB at +1MB

    wt_kernel    <<<dim3(32, 8), dim3(32, 32), 0, stream>>>(W, WT);
    gemm_kernel  <<<dim3(M_TOT / 64), dim3(256), 0, stream>>>(A, WT, bias, H);
    gather_kernel<<<dim3(NQ_), dim3(256), 0, stream>>>(H, s1, e1, qb, s2, e2, out);
}